// Round 16
// baseline (774.134 us; speedup 1.0000x reference)
//
#include <hip/hip_runtime.h>
#include <hip/hip_bf16.h>
#include <math.h>

#define S_LEN 1024
#define HDIM  768
#define NPROC 4
#define VOCAB 50257
#define KSTEPS 4

typedef __attribute__((ext_vector_type(4))) float f32x4;
typedef __attribute__((ext_vector_type(8))) short bf16x8;
typedef __attribute__((ext_vector_type(4))) short short4v;

static __device__ __forceinline__ ushort f2bf(float f) {
  union { __hip_bfloat16 b; ushort u; } cv;
  cv.b = __float2bfloat16(f);
  return cv.u;
}

#define GLOAD16(gp, lp) __builtin_amdgcn_global_load_lds( \
    (const __attribute__((address_space(1))) unsigned int*)(gp), \
    (__attribute__((address_space(3))) unsigned int*)(lp), 16, 0, 0)

// ---------------- prep: weight converts (lmw+W1+W2) + fused LN(k=0), one dispatch --------
__global__ __launch_bounds__(256) void prep_weights(
    const float* __restrict__ lmw, const float* __restrict__ W1,
    const float* __restrict__ W2, ushort* __restrict__ lm_bf,
    ushort* __restrict__ w1_bf, ushort* __restrict__ w2_bf,
    const float* __restrict__ hidden, const int* __restrict__ mask,
    const float* __restrict__ alphap, const float* __restrict__ gamma,
    const float* __restrict__ beta, ushort* __restrict__ normed) {
  const int LM4 = VOCAB * HDIM / 4;
  const int W4  = HDIM * HDIM / 4;
  const int LMB = (LM4 + 255) / 256;
  const int WB  = (W4 + 255) / 256;
  const int bid = blockIdx.x;
  const int tid = threadIdx.x;
  __shared__ float rs_[4], rq_[4];
  if (bid < LMB + 2 * WB) {
    const float* in; ushort* out; int n4, i;
    if (bid < LMB)           { in = lmw; out = lm_bf; n4 = LM4; i = bid * 256 + tid; }
    else if (bid < LMB + WB) { in = W1;  out = w1_bf; n4 = W4;  i = (bid - LMB) * 256 + tid; }
    else                     { in = W2;  out = w2_bf; n4 = W4;  i = (bid - LMB - WB) * 256 + tid; }
    if (i >= n4) return;
    f32x4 v = ((const f32x4*)in)[i];
    short4v o;
#pragma unroll
    for (int j = 0; j < 4; j++) o[j] = (short)f2bf(v[j]);
    ((short4v*)out)[i] = o;
  } else {
    // ---- LN for k=0 on hidden ----
    const int s = bid - (LMB + 2 * WB);
    const float mk = (float)mask[s];
    const float a1 = 1.0f + alphap[0];
    float merged[3];
    float lsum = 0.f, lsq = 0.f;
#pragma unroll
    for (int e = 0; e < 3; e++) {
      const int h = tid + e * 256;
      float mg = hidden[(size_t)s * HDIM + h] * mk * a1;
      merged[e] = mg;
      lsum += mg;
      lsq += mg * mg;
    }
#pragma unroll
    for (int off = 32; off > 0; off >>= 1) {
      lsum += __shfl_down(lsum, off, 64);
      lsq  += __shfl_down(lsq, off, 64);
    }
    const int wv = tid >> 6, ln = tid & 63;
    if (ln == 0) { rs_[wv] = lsum; rq_[wv] = lsq; }
    __syncthreads();
    const float ts = rs_[0] + rs_[1] + rs_[2] + rs_[3];
    const float tq = rq_[0] + rq_[1] + rq_[2] + rq_[3];
    const float mu = ts * (1.f / HDIM);
    const float var = tq * (1.f / HDIM) - mu * mu;
    const float rstd = rsqrtf(var + 1e-5f);
#pragma unroll
    for (int e = 0; e < 3; e++) {
      const int h = tid + e * 256;
      float nv = (merged[e] - mu) * rstd * gamma[h] + beta[h];
      normed[(size_t)s * HDIM + h] = f2bf(nv);
    }
  }
}

// ---------------- flat broadcast logits -> plogits[0..3] ----------------
__global__ __launch_bounds__(256) void bcast_logits(
    const float* __restrict__ src, float* __restrict__ dst) {
  const size_t n4 = (size_t)S_LEN * VOCAB / 4;
  for (size_t i = (size_t)blockIdx.x * 256 + threadIdx.x; i < n4;
       i += (size_t)gridDim.x * 256) {
    f32x4 v = ((const f32x4*)src)[i];
#pragma unroll
    for (int p = 0; p < NPROC; p++)
      ((f32x4*)dst)[(size_t)p * n4 + i] = v;
  }
}

// ---------------- P=1 merge + LayerNorm -> bf16 (k>0, reads st1) ----------------
__global__ __launch_bounds__(256) void merge_ln_p1(
    const float* __restrict__ src, const int* __restrict__ mask,
    const float* __restrict__ alphap, const float* __restrict__ gamma,
    const float* __restrict__ beta, ushort* __restrict__ normed) {
  const int s = blockIdx.x;
  const int tid = threadIdx.x;
  const float mk = (float)mask[s];
  const float a1 = 1.0f + alphap[0];
  float merged[3];
  float lsum = 0.f, lsq = 0.f;
#pragma unroll
  for (int e = 0; e < 3; e++) {
    const int h = tid + e * 256;
    float mg = src[(size_t)s * HDIM + h] * mk * a1;
    merged[e] = mg;
    lsum += mg;
    lsq += mg * mg;
  }
#pragma unroll
  for (int off = 32; off > 0; off >>= 1) {
    lsum += __shfl_down(lsum, off, 64);
    lsq  += __shfl_down(lsq, off, 64);
  }
  __shared__ float rs_[4], rq_[4];
  const int wv = tid >> 6, ln = tid & 63;
  if (ln == 0) { rs_[wv] = lsum; rq_[wv] = lsq; }
  __syncthreads();
  const float ts = rs_[0] + rs_[1] + rs_[2] + rs_[3];
  const float tq = rq_[0] + rq_[1] + rq_[2] + rq_[3];
  const float mu = ts * (1.f / HDIM);
  const float var = tq * (1.f / HDIM) - mu * mu;
  const float rstd = rsqrtf(var + 1e-5f);
#pragma unroll
  for (int e = 0; e < 3; e++) {
    const int h = tid + e * 256;
    float nv = (merged[e] - mu) * rstd * gamma[h] + beta[h];
    normed[(size_t)s * HDIM + h] = f2bf(nv);
  }
}

// ---------------- MLP GEMM  C[M=1024,N=768] = A * B^T, 128x64 tile, BK=32, ring-3 -------
template <int MODE>
__global__ __launch_bounds__(256, 4) void gemm_mlp(
    const ushort* __restrict__ A, const ushort* __restrict__ B,
    const float* __restrict__ bias, ushort* __restrict__ out_bf,
    const float* __restrict__ src, float* __restrict__ dst,
    float* __restrict__ states, const int* __restrict__ mask) {
  __shared__ __align__(16) ushort lsA[3][4096];
  __shared__ __align__(16) ushort lsB[3][2048];
  const int tid = threadIdx.x;
  const int bx = blockIdx.x;
  const int mt = bx & 7;
  const int nt = bx >> 3;
  const int wv = tid >> 6, lane = tid & 63;
  const int wm = wv >> 1, wn = wv & 1;
  const int g = lane >> 4, lr = lane & 15;

  f32x4 acc[4][2];
#pragma unroll
  for (int i = 0; i < 4; i++)
#pragma unroll
    for (int j = 0; j < 2; j++) acc[i][j] = (f32x4){0.f, 0.f, 0.f, 0.f};

  const int koff = (tid & 3) * 8;
  const int arow0 = mt * 128 + (tid >> 2);
  const ushort* gA0 = A + (size_t)arow0 * HDIM + koff;
  const ushort* gA1 = gA0 + (size_t)64 * HDIM;
  const ushort* gB0 = B + (size_t)(nt * 64 + (tid >> 2)) * HDIM + koff;
  const int dstl = (tid >> 2) * 32 + (tid & 3) * 8;

#define STAGE(kt, buf) do {                      \
    const int o_ = (kt) * 32;                    \
    GLOAD16(gA0 + o_, &lsA[buf][dstl]);          \
    GLOAD16(gA1 + o_, &lsA[buf][2048 + dstl]);   \
    GLOAD16(gB0 + o_, &lsB[buf][dstl]);          \
  } while (0)

  constexpr int NT = HDIM / 32;  // 24
  STAGE(0, 0);
  STAGE(1, 1);
  STAGE(2, 2);
  int cur = 0;
  for (int kt = 0; kt < NT; ++kt) {
    if (kt < NT - 2)      asm volatile("s_waitcnt vmcnt(6)" ::: "memory");
    else if (kt == NT - 2) asm volatile("s_waitcnt vmcnt(3)" ::: "memory");
    else                  asm volatile("s_waitcnt vmcnt(0)" ::: "memory");
    __builtin_amdgcn_s_barrier();
    __builtin_amdgcn_sched_barrier(0);
    bf16x8 af[4], bfr[2];
#pragma unroll
    for (int mi = 0; mi < 4; mi++)
      af[mi] = *(const bf16x8*)(&lsA[cur][(wm * 64 + mi * 16 + lr) * 32 + g * 8]);
#pragma unroll
    for (int ni = 0; ni < 2; ni++)
      bfr[ni] = *(const bf16x8*)(&lsB[cur][(wn * 32 + ni * 16 + lr) * 32 + g * 8]);
    asm volatile("s_waitcnt lgkmcnt(0)" ::: "memory");
    __builtin_amdgcn_sched_barrier(0);
    __builtin_amdgcn_s_setprio(1);
#pragma unroll
    for (int mi = 0; mi < 4; mi++)
#pragma unroll
      for (int ni = 0; ni < 2; ni++)
        acc[mi][ni] = __builtin_amdgcn_mfma_f32_16x16x32_bf16(af[mi], bfr[ni], acc[mi][ni], 0, 0, 0);
    __builtin_amdgcn_s_setprio(0);
    __builtin_amdgcn_s_barrier();
    __builtin_amdgcn_sched_barrier(0);
    if (kt + 3 < NT) STAGE(kt + 3, cur);
    cur = (cur == 2) ? 0 : cur + 1;
  }
#undef STAGE

#pragma unroll
  for (int mi = 0; mi < 4; mi++) {
    const int mrow = mt * 128 + wm * 64 + mi * 16 + g * 4;
#pragma unroll
    for (int ni = 0; ni < 2; ni++) {
      const int ncol = nt * 64 + wn * 32 + ni * 16 + lr;
      const float bv = bias[ncol];
      if (MODE == 0) {
#pragma unroll
        for (int j = 0; j < 4; j++) {
          float x = acc[mi][ni][j] + bv;
          float ge = 0.5f * x * (1.f + erff(x * 0.70710678118654752f));
          out_bf[(size_t)(mrow + j) * HDIM + ncol] = f2bf(ge);
        }
      } else {
#pragma unroll
        for (int j = 0; j < 4; j++) {
          const int m = mrow + j;
          const float mk = (float)mask[m];
          const size_t idx = (size_t)m * HDIM + ncol;
          const float mut = src[idx] * mk;
          const float ns = (mut + acc[mi][ni][j] + bv) * mk;
          if (out_bf) {
            out_bf[idx] = f2bf(ns);
#pragma unroll
            for (int p = 0; p < NPROC; p++)
              states[(size_t)p * S_LEN * HDIM + idx] = ns;
          } else {
            dst[idx] = ns;
          }
        }
      }
    }
  }
}

// ---------------- LM-head GEMM: A-resident persistent kernel ----------------------------
// C[1024, 50257] = A[1024,768] * B[50257,768]^T. Grid = 256 blocks = 1/CU, 4 waves.
// Block (m = bx&15, grp = bx>>4): A-tile (64 rows x 768, 96 KB) resident in LDS (staged
// once); iterates ~25 n-tiles of 128 cols; B streamed via ring-4 8KB LDS tiles with
// counted vmcnt (2 loads/tile, depth-3). XOR slot swizzle (p = s ^ (row&3)) on both sides.
// Per wave: 32x64 output (acc[2][4]); direct 64B-coalesced dword stores per iteration.
__global__ __launch_bounds__(256, 1) void gemm_lm(
    const ushort* __restrict__ A, const ushort* __restrict__ B,
    float* __restrict__ logits) {
  __shared__ __align__(16) ushort lsA[49152];    // [24 kt][64 rows][4 slots x 8]
  __shared__ __align__(16) ushort lsB[4][4096];  // ring-4: [128 rows][4 slots x 8]
  const int tid = threadIdx.x;
  const int bx = blockIdx.x;
  const int m0 = (bx & 15) * 64;
  const int grp = bx >> 4;
  constexpr int NTILES = (VOCAB + 127) / 128;    // 393
  constexpr int QCH = (NTILES + 15) / 16;        // 25
  const int nt0 = grp * QCH;
  const int nt1 = (nt0 + QCH < NTILES) ? nt0 + QCH : NTILES;
  const int wv = tid >> 6, lane = tid & 63;
  const int wm = wv >> 1, wn = wv & 1;
  const int g = lane >> 4, lr = lane & 15;

  // ---- stage A once: 96 KB = 6144 chunks of 16B, 24 rounds ----
#pragma unroll
  for (int r = 0; r < 24; r++) {
    const int c = r * 256 + wv * 64 + lane;
    const int kt = c >> 8, cc = c & 255, row = cc >> 2, p = cc & 3;
    const int s = p ^ (row & 3);
    GLOAD16(A + (size_t)(m0 + row) * HDIM + kt * 32 + s * 8,
            lsA + (size_t)(r * 256 + wv * 64) * 8);
  }

#define STGB(ntv, tv, sl) do {                                            \
    _Pragma("unroll")                                                     \
    for (int jj = 0; jj < 2; jj++) {                                      \
      const int c_ = jj * 256 + wv * 64 + lane;                           \
      const int row_ = c_ >> 2, p_ = c_ & 3;                              \
      const int s_ = p_ ^ (row_ & 3);                                     \
      int rg_ = (ntv) * 128 + row_; if (rg_ >= VOCAB) rg_ = VOCAB - 1;    \
      GLOAD16(B + (size_t)rg_ * HDIM + (tv) * 32 + s_ * 8,                \
              &lsB[sl][(size_t)(jj * 256 + wv * 64) * 8]);                \
    }                                                                     \
  } while (0)

  // B prologue for first n-tile
  STGB(nt0, 0, 0); STGB(nt0, 1, 1); STGB(nt0, 2, 2);

  f32x4 acc[2][4];
#pragma unroll
  for (int i = 0; i < 2; i++)
#pragma unroll
    for (int j = 0; j < 4; j++) acc[i][j] = (f32x4){0.f, 0.f, 0.f, 0.f};

  const int xslot = ((lr & 3)) << 3;  // XOR base; logical slot g -> ushort off ((g^(lr&3))*8)
  constexpr int NKT = HDIM / 32;      // 24

  for (int nt = nt0; nt < nt1; ++nt) {
    for (int t = 0; t < NKT; ++t) {
      if (t < NKT - 2)       asm volatile("s_waitcnt vmcnt(4)" ::: "memory");
      else if (t == NKT - 2) asm volatile("s_waitcnt vmcnt(2)" ::: "memory");
      else                   asm volatile("s_waitcnt vmcnt(0)" ::: "memory");
      __builtin_amdgcn_sched_barrier(0);
      __builtin_amdgcn_s_barrier();
      __builtin_amdgcn_sched_barrier(0);
      const int sl = t & 3;
      bf16x8 af[2], bfr[4];
#pragma unroll
      for (int mi = 0; mi < 2; mi++)
        af[mi] = *(const bf16x8*)(lsA + t * 2048 + (wm * 32 + mi * 16 + lr) * 32 +
                                  ((g << 3) ^ xslot));
#pragma unroll
      for (int ni = 0; ni < 4; ni++)
        bfr[ni] = *(const bf16x8*)(&lsB[sl][(wn * 64 + ni * 16 + lr) * 32 +
                                            ((g << 3) ^ xslot)]);
      asm volatile("s_waitcnt lgkmcnt(0)" ::: "memory");
      __builtin_amdgcn_sched_barrier(0);
      __builtin_amdgcn_s_setprio(1);
#pragma unroll
      for (int mi = 0; mi < 2; mi++)
#pragma unroll
        for (int ni = 0; ni < 4; ni++)
          acc[mi][ni] = __builtin_amdgcn_mfma_f32_16x16x32_bf16(af[mi], bfr[ni], acc[mi][ni], 0, 0, 0);
      __builtin_amdgcn_s_setprio(0);
      __builtin_amdgcn_s_barrier();
      __builtin_amdgcn_sched_barrier(0);
      if (t + 3 < NKT) STGB(nt, t + 3, (t + 3) & 3);
    }
    // all tiles consumed by all waves before restaging slots 0..2
    __builtin_amdgcn_s_barrier();
    if (nt + 1 < nt1) { STGB(nt + 1, 0, 0); STGB(nt + 1, 1, 1); STGB(nt + 1, 2, 2); }
    // epilogue: direct stores (issued after next prologue loads -> FIFO drains loads first)
    const int n0 = nt * 128;
#pragma unroll
    for (int mi = 0; mi < 2; mi++) {
      const int row0 = m0 + wm * 32 + mi * 16 + g * 4;
#pragma unroll
      for (int ni = 0; ni < 4; ni++) {
        const int col = n0 + wn * 64 + ni * 16 + lr;
        if (col < VOCAB) {
#pragma unroll
          for (int j = 0; j < 4; j++)
            logits[(size_t)(row0 + j) * VOCAB + col] = acc[mi][ni][j];
        }
        acc[mi][ni] = (f32x4){0.f, 0.f, 0.f, 0.f};
      }
    }
  }
#undef STGB
}

extern "C" void kernel_launch(void* const* d_in, const int* in_sizes, int n_in,
                              void* d_out, int out_size, void* d_ws, size_t ws_size,
                              hipStream_t stream) {
  const float* hidden = (const float*)d_in[0];
  const int*   mask   = (const int*)d_in[1];
  const float* alphap = (const float*)d_in[2];
  const float* gamma  = (const float*)d_in[3];
  const float* beta   = (const float*)d_in[4];
  const float* W1     = (const float*)d_in[5];
  const float* b1     = (const float*)d_in[6];
  const float* W2     = (const float*)d_in[7];
  const float* b2     = (const float*)d_in[8];
  const float* lmw    = (const float*)d_in[9];

  float* logits  = (float*)d_out;
  float* plogits = logits + (size_t)S_LEN * VOCAB;
  float* states  = plogits + (size_t)NPROC * S_LEN * VOCAB;

  uint8_t* ws = (uint8_t*)d_ws;
  ushort* lm_bf  = (ushort*)ws;                       // 77,194,752 B
  ushort* w1_bf  = (ushort*)(ws + 77194752);          // 1,179,648 B
  ushort* w2_bf  = (ushort*)(ws + 78374400);          // 1,179,648 B
  ushort* nrm_bf = (ushort*)(ws + 79554048);          // 1,572,864 B
  ushort* h_bf   = (ushort*)(ws + 81126912);          // 1,572,864 B
  ushort* a_bf   = (ushort*)(ws + 82699776);          // 1,572,864 B
  float*  st1    = (float*) (ws + 84272640);          // 3,145,728 B
  if (ws_size < 87418368) return;

  const int LMB = (VOCAB * HDIM / 4 + 255) / 256, WB = (HDIM * HDIM / 4 + 255) / 256;
  prep_weights<<<LMB + 2 * WB + S_LEN, 256, 0, stream>>>(
      lmw, W1, W2, lm_bf, w1_bf, w2_bf, hidden, mask, alphap, gamma, beta, nrm_bf);

  for (int k = 0; k < KSTEPS; k++) {
    const float* src = (k == 0) ? hidden : st1;
    if (k > 0)
      merge_ln_p1<<<S_LEN, 256, 0, stream>>>(src, mask, alphap, gamma, beta, nrm_bf);
    gemm_mlp<0><<<(HDIM / 64) * 8, 256, 0, stream>>>(
        nrm_bf, w1_bf, b1, h_bf, nullptr, nullptr, nullptr, mask);
    gemm_mlp<1><<<(HDIM / 64) * 8, 256, 0, stream>>>(
        h_bf, w2_bf, b2, (k == KSTEPS - 1) ? (ushort*)a_bf : nullptr,
        src, st1, states, mask);
  }
  gemm_lm<<<256, 256, 0, stream>>>(a_bf, lm_bf, logits);
  bcast_logits<<<2048, 256, 0, stream>>>(logits, plogits);
}

// Round 17
// 598.243 us; speedup vs baseline: 1.2940x; 1.2940x over previous
//
#include <hip/hip_runtime.h>
#include <hip/hip_bf16.h>
#include <math.h>

#define S_LEN 1024
#define HDIM  768
#define NPROC 4
#define VOCAB 50257
#define KSTEPS 4

typedef __attribute__((ext_vector_type(4))) float f32x4;
typedef __attribute__((ext_vector_type(8))) short bf16x8;
typedef __attribute__((ext_vector_type(4))) short short4v;

static __device__ __forceinline__ ushort f2bf(float f) {
  union { __hip_bfloat16 b; ushort u; } cv;
  cv.b = __float2bfloat16(f);
  return cv.u;
}

#define GLOAD16(gp, lp) __builtin_amdgcn_global_load_lds( \
    (const __attribute__((address_space(1))) unsigned int*)(gp), \
    (__attribute__((address_space(3))) unsigned int*)(lp), 16, 0, 0)

// ---------------- prep: weight converts (lmw+W1+W2) + fused LN(k=0), one dispatch --------
__global__ __launch_bounds__(256) void prep_weights(
    const float* __restrict__ lmw, const float* __restrict__ W1,
    const float* __restrict__ W2, ushort* __restrict__ lm_bf,
    ushort* __restrict__ w1_bf, ushort* __restrict__ w2_bf,
    const float* __restrict__ hidden, const int* __restrict__ mask,
    const float* __restrict__ alphap, const float* __restrict__ gamma,
    const float* __restrict__ beta, ushort* __restrict__ normed) {
  const int LM4 = VOCAB * HDIM / 4;
  const int W4  = HDIM * HDIM / 4;
  const int LMB = (LM4 + 255) / 256;
  const int WB  = (W4 + 255) / 256;
  const int bid = blockIdx.x;
  const int tid = threadIdx.x;
  __shared__ float rs_[4], rq_[4];
  if (bid < LMB + 2 * WB) {
    const float* in; ushort* out; int n4, i;
    if (bid < LMB)           { in = lmw; out = lm_bf; n4 = LM4; i = bid * 256 + tid; }
    else if (bid < LMB + WB) { in = W1;  out = w1_bf; n4 = W4;  i = (bid - LMB) * 256 + tid; }
    else                     { in = W2;  out = w2_bf; n4 = W4;  i = (bid - LMB - WB) * 256 + tid; }
    if (i >= n4) return;
    f32x4 v = ((const f32x4*)in)[i];
    short4v o;
#pragma unroll
    for (int j = 0; j < 4; j++) o[j] = (short)f2bf(v[j]);
    ((short4v*)out)[i] = o;
  } else {
    // ---- LN for k=0 on hidden ----
    const int s = bid - (LMB + 2 * WB);
    const float mk = (float)mask[s];
    const float a1 = 1.0f + alphap[0];
    float merged[3];
    float lsum = 0.f, lsq = 0.f;
#pragma unroll
    for (int e = 0; e < 3; e++) {
      const int h = tid + e * 256;
      float mg = hidden[(size_t)s * HDIM + h] * mk * a1;
      merged[e] = mg;
      lsum += mg;
      lsq += mg * mg;
    }
#pragma unroll
    for (int off = 32; off > 0; off >>= 1) {
      lsum += __shfl_down(lsum, off, 64);
      lsq  += __shfl_down(lsq, off, 64);
    }
    const int wv = tid >> 6, ln = tid & 63;
    if (ln == 0) { rs_[wv] = lsum; rq_[wv] = lsq; }
    __syncthreads();
    const float ts = rs_[0] + rs_[1] + rs_[2] + rs_[3];
    const float tq = rq_[0] + rq_[1] + rq_[2] + rq_[3];
    const float mu = ts * (1.f / HDIM);
    const float var = tq * (1.f / HDIM) - mu * mu;
    const float rstd = rsqrtf(var + 1e-5f);
#pragma unroll
    for (int e = 0; e < 3; e++) {
      const int h = tid + e * 256;
      float nv = (merged[e] - mu) * rstd * gamma[h] + beta[h];
      normed[(size_t)s * HDIM + h] = f2bf(nv);
    }
  }
}

// ---------------- flat broadcast logits -> plogits[0..3] ----------------
__global__ __launch_bounds__(256) void bcast_logits(
    const float* __restrict__ src, float* __restrict__ dst) {
  const size_t n4 = (size_t)S_LEN * VOCAB / 4;
  for (size_t i = (size_t)blockIdx.x * 256 + threadIdx.x; i < n4;
       i += (size_t)gridDim.x * 256) {
    f32x4 v = ((const f32x4*)src)[i];
#pragma unroll
    for (int p = 0; p < NPROC; p++)
      ((f32x4*)dst)[(size_t)p * n4 + i] = v;
  }
}

// ---------------- P=1 merge + LayerNorm -> bf16 (k>0, reads st1) ----------------
__global__ __launch_bounds__(256) void merge_ln_p1(
    const float* __restrict__ src, const int* __restrict__ mask,
    const float* __restrict__ alphap, const float* __restrict__ gamma,
    const float* __restrict__ beta, ushort* __restrict__ normed) {
  const int s = blockIdx.x;
  const int tid = threadIdx.x;
  const float mk = (float)mask[s];
  const float a1 = 1.0f + alphap[0];
  float merged[3];
  float lsum = 0.f, lsq = 0.f;
#pragma unroll
  for (int e = 0; e < 3; e++) {
    const int h = tid + e * 256;
    float mg = src[(size_t)s * HDIM + h] * mk * a1;
    merged[e] = mg;
    lsum += mg;
    lsq += mg * mg;
  }
#pragma unroll
  for (int off = 32; off > 0; off >>= 1) {
    lsum += __shfl_down(lsum, off, 64);
    lsq  += __shfl_down(lsq, off, 64);
  }
  __shared__ float rs_[4], rq_[4];
  const int wv = tid >> 6, ln = tid & 63;
  if (ln == 0) { rs_[wv] = lsum; rq_[wv] = lsq; }
  __syncthreads();
  const float ts = rs_[0] + rs_[1] + rs_[2] + rs_[3];
  const float tq = rq_[0] + rq_[1] + rq_[2] + rq_[3];
  const float mu = ts * (1.f / HDIM);
  const float var = tq * (1.f / HDIM) - mu * mu;
  const float rstd = rsqrtf(var + 1e-5f);
#pragma unroll
  for (int e = 0; e < 3; e++) {
    const int h = tid + e * 256;
    float nv = (merged[e] - mu) * rstd * gamma[h] + beta[h];
    normed[(size_t)s * HDIM + h] = f2bf(nv);
  }
}

// ---------------- GEMM core: C[128xM-tile, 64xN-tile] = A*B^T, BK=32, ring-3 depth-2 ----
// MODE 0: MLP1 (+b1, exact GELU -> bf16 h)
// MODE 1: MLP2 (+b2, ns=(src*mask+C)*mask -> st1; last step: bf16 out + states fanout)
// MODE 2: LM head (no bias; logits dword stores, col-bounds-checked; nrowsB = VOCAB)
template <int MODE>
__global__ __launch_bounds__(256, 4) void gemm_bt(
    const ushort* __restrict__ A, const ushort* __restrict__ B,
    const float* __restrict__ bias, ushort* __restrict__ out_bf,
    const float* __restrict__ src, float* __restrict__ dst,
    float* __restrict__ states, const int* __restrict__ mask, int nrowsB) {
  __shared__ __align__(16) ushort lsA[3][4096];
  __shared__ __align__(16) ushort lsB[3][2048];
  const int tid = threadIdx.x;
  const int bx = blockIdx.x;
  const int mt = bx & 7;    // 8 m-tiles of 128 (M=1024); bid%8=mt -> per-XCD A locality
  const int nt = bx >> 3;   // n-tiles of 64
  const int wv = tid >> 6, lane = tid & 63;
  const int wm = wv >> 1, wn = wv & 1;
  const int g = lane >> 4, lr = lane & 15;

  f32x4 acc[4][2];
#pragma unroll
  for (int i = 0; i < 4; i++)
#pragma unroll
    for (int j = 0; j < 2; j++) acc[i][j] = (f32x4){0.f, 0.f, 0.f, 0.f};

  const int koff = (tid & 3) * 8;
  const int arow0 = mt * 128 + (tid >> 2);
  const ushort* gA0 = A + (size_t)arow0 * HDIM + koff;
  const ushort* gA1 = gA0 + (size_t)64 * HDIM;
  int brow = nt * 64 + (tid >> 2);
  if (MODE == 2 && brow >= nrowsB) brow = nrowsB - 1;
  const ushort* gB0 = B + (size_t)brow * HDIM + koff;
  const int dstl = (tid >> 2) * 32 + (tid & 3) * 8;

#define STAGE(kt, buf) do {                      \
    const int o_ = (kt) * 32;                    \
    GLOAD16(gA0 + o_, &lsA[buf][dstl]);          \
    GLOAD16(gA1 + o_, &lsA[buf][2048 + dstl]);   \
    GLOAD16(gB0 + o_, &lsB[buf][dstl]);          \
  } while (0)

  constexpr int NT = HDIM / 32;  // 24
  STAGE(0, 0);
  STAGE(1, 1);
  STAGE(2, 2);
  int cur = 0;
  for (int kt = 0; kt < NT; ++kt) {
    if (kt < NT - 2)       asm volatile("s_waitcnt vmcnt(6)" ::: "memory");
    else if (kt == NT - 2) asm volatile("s_waitcnt vmcnt(3)" ::: "memory");
    else                   asm volatile("s_waitcnt vmcnt(0)" ::: "memory");
    __builtin_amdgcn_s_barrier();
    __builtin_amdgcn_sched_barrier(0);
    bf16x8 af[4], bfr[2];
#pragma unroll
    for (int mi = 0; mi < 4; mi++)
      af[mi] = *(const bf16x8*)(&lsA[cur][(wm * 64 + mi * 16 + lr) * 32 + g * 8]);
#pragma unroll
    for (int ni = 0; ni < 2; ni++)
      bfr[ni] = *(const bf16x8*)(&lsB[cur][(wn * 32 + ni * 16 + lr) * 32 + g * 8]);
    asm volatile("s_waitcnt lgkmcnt(0)" ::: "memory");
    __builtin_amdgcn_sched_barrier(0);
    __builtin_amdgcn_s_setprio(1);
#pragma unroll
    for (int mi = 0; mi < 4; mi++)
#pragma unroll
      for (int ni = 0; ni < 2; ni++)
        acc[mi][ni] = __builtin_amdgcn_mfma_f32_16x16x32_bf16(af[mi], bfr[ni], acc[mi][ni], 0, 0, 0);
    __builtin_amdgcn_s_setprio(0);
    __builtin_amdgcn_s_barrier();
    __builtin_amdgcn_sched_barrier(0);
    if (kt + 3 < NT) STAGE(kt + 3, cur);
    cur = (cur == 2) ? 0 : cur + 1;
  }
#undef STAGE

#pragma unroll
  for (int mi = 0; mi < 4; mi++) {
    const int mrow = mt * 128 + wm * 64 + mi * 16 + g * 4;
#pragma unroll
    for (int ni = 0; ni < 2; ni++) {
      const int ncol = nt * 64 + wn * 32 + ni * 16 + lr;
      if (MODE == 0) {
        const float bv = bias[ncol];
#pragma unroll
        for (int j = 0; j < 4; j++) {
          float x = acc[mi][ni][j] + bv;
          float ge = 0.5f * x * (1.f + erff(x * 0.70710678118654752f));
          out_bf[(size_t)(mrow + j) * HDIM + ncol] = f2bf(ge);
        }
      } else if (MODE == 1) {
        const float bv = bias[ncol];
#pragma unroll
        for (int j = 0; j < 4; j++) {
          const int m = mrow + j;   // m == s at P=1
          const float mk = (float)mask[m];
          const size_t idx = (size_t)m * HDIM + ncol;
          const float mut = src[idx] * mk;
          const float ns = (mut + acc[mi][ni][j] + bv) * mk;
          if (out_bf) {
            out_bf[idx] = f2bf(ns);
#pragma unroll
            for (int p = 0; p < NPROC; p++)
              states[(size_t)p * S_LEN * HDIM + idx] = ns;
          } else {
            dst[idx] = ns;
          }
        }
      } else {
        if (ncol < nrowsB) {
#pragma unroll
          for (int j = 0; j < 4; j++)
            dst[(size_t)(mrow + j) * VOCAB + ncol] = acc[mi][ni][j];
        }
      }
    }
  }
}

extern "C" void kernel_launch(void* const* d_in, const int* in_sizes, int n_in,
                              void* d_out, int out_size, void* d_ws, size_t ws_size,
                              hipStream_t stream) {
  const float* hidden = (const float*)d_in[0];
  const int*   mask   = (const int*)d_in[1];
  const float* alphap = (const float*)d_in[2];
  const float* gamma  = (const float*)d_in[3];
  const float* beta   = (const float*)d_in[4];
  const float* W1     = (const float*)d_in[5];
  const float* b1     = (const float*)d_in[6];
  const float* W2     = (const float*)d_in[7];
  const float* b2     = (const float*)d_in[8];
  const float* lmw    = (const float*)d_in[9];

  float* logits  = (float*)d_out;
  float* plogits = logits + (size_t)S_LEN * VOCAB;
  float* states  = plogits + (size_t)NPROC * S_LEN * VOCAB;

  uint8_t* ws = (uint8_t*)d_ws;
  ushort* lm_bf  = (ushort*)ws;                       // 77,194,752 B
  ushort* w1_bf  = (ushort*)(ws + 77194752);          // 1,179,648 B
  ushort* w2_bf  = (ushort*)(ws + 78374400);          // 1,179,648 B
  ushort* nrm_bf = (ushort*)(ws + 79554048);          // 1,572,864 B
  ushort* h_bf   = (ushort*)(ws + 81126912);          // 1,572,864 B
  ushort* a_bf   = (ushort*)(ws + 82699776);          // 1,572,864 B
  float*  st1    = (float*) (ws + 84272640);          // 3,145,728 B
  if (ws_size < 87418368) return;

  const int LMB = (VOCAB * HDIM / 4 + 255) / 256, WB = (HDIM * HDIM / 4 + 255) / 256;
  prep_weights<<<LMB + 2 * WB + S_LEN, 256, 0, stream>>>(
      lmw, W1, W2, lm_bf, w1_bf, w2_bf, hidden, mask, alphap, gamma, beta, nrm_bf);

  for (int k = 0; k < KSTEPS; k++) {
    const float* src = (k == 0) ? hidden : st1;
    if (k > 0)
      merge_ln_p1<<<S_LEN, 256, 0, stream>>>(src, mask, alphap, gamma, beta, nrm_bf);
    gemm_bt<0><<<(HDIM / 64) * 8, 256, 0, stream>>>(
        nrm_bf, w1_bf, b1, h_bf, nullptr, nullptr, nullptr, mask, HDIM);
    gemm_bt<1><<<(HDIM / 64) * 8, 256, 0, stream>>>(
        h_bf, w2_bf, b2, (k == KSTEPS - 1) ? (ushort*)a_bf : nullptr,
        src, st1, states, mask, HDIM);
  }
  // LM head: same proven 4-blk/CU structure; 8 mt x 786 nt = 6288 blocks
  gemm_bt<2><<<((VOCAB + 63) / 64) * 8, 256, 0, stream>>>(
      a_bf, lm_bf, nullptr, nullptr, nullptr, logits, nullptr, nullptr, VOCAB);
  bcast_logits<<<2048, 256, 0, stream>>>(logits, plogits);
}